// Round 1
// baseline (292.674 us; speedup 1.0000x reference)
//
#include <hip/hip_runtime.h>
#include <math.h>

#define B 16
#define S 2048
#define C 1024
#define H 8
#define HD 128

// ---------------------------------------------------------------------------
// k1: qk[b,h,d] = sum_e q[b,h,e] * Wk[e,d],  q[b,h,e] = pref[b,h]*Wq[e]+bq[e]
// (the q·bk term is softmax-shift-invariant and dropped)
// ---------------------------------------------------------------------------
__global__ void k1_qk(const float* __restrict__ pref, const float* __restrict__ Wq,
                      const float* __restrict__ bq, const float* __restrict__ Wk,
                      float* __restrict__ qk) {
    int bh = blockIdx.x;            // b*H + h
    int d  = threadIdx.x;           // 0..127
    __shared__ float qsh[HD];
    float p = pref[bh];
    qsh[d] = p * Wq[d] + bq[d];
    __syncthreads();
    float s = 0.f;
#pragma unroll 8
    for (int e = 0; e < HD; ++e)
        s += qsh[e] * Wk[e * HD + d];      // coalesced across d
    qk[bh * HD + d] = s;
}

// ---------------------------------------------------------------------------
// k2: one streaming pass over features. Per block: one (b, s-chunk) of R rows.
// Thread t (0..255) loads float4 at column 4t -> head h = t>>5.
// Per row: 32-lane butterfly reduce -> score; online softmax update of
// (m, l, fbar[4]) kept in registers. Partials written to ws.
// ---------------------------------------------------------------------------
__global__ __launch_bounds__(256) void k2_pass(
    const float* __restrict__ feat, const float* __restrict__ qk,
    float* __restrict__ pm, float* __restrict__ pl, float* __restrict__ pf,
    int NC, int R) {
    int wg    = blockIdx.x;          // b*NC + chunk
    int b     = wg / NC;
    int chunk = wg - b * NC;
    int t     = threadIdx.x;         // 0..255
    int h     = t >> 5;
    int lane32 = t & 31;

    const float4* frow = (const float4*)feat
                       + (size_t)(b * S + chunk * R) * (C / 4) + t;
    float4 qv = ((const float4*)qk)[(b * H + h) * (HD / 4) + lane32];

    float m = -1e30f, l = 0.f;
    float a0 = 0.f, a1 = 0.f, a2 = 0.f, a3 = 0.f;

    for (int s = 0; s < R; ++s) {
        float4 f = frow[(size_t)s * (C / 4)];
        float part = f.x * qv.x + f.y * qv.y + f.z * qv.z + f.w * qv.w;
        part += __shfl_xor(part, 16, 32);
        part += __shfl_xor(part, 8, 32);
        part += __shfl_xor(part, 4, 32);
        part += __shfl_xor(part, 2, 32);
        part += __shfl_xor(part, 1, 32);     // all 32 lanes hold the score
        float mn    = fmaxf(m, part);
        float scale = __expf(m - mn);
        float p     = __expf(part - mn);
        l  = l * scale + p;
        a0 = a0 * scale + p * f.x;
        a1 = a1 * scale + p * f.y;
        a2 = a2 * scale + p * f.z;
        a3 = a3 * scale + p * f.w;
        m  = mn;
    }
    if (lane32 == 0) { pm[wg * H + h] = m; pl[wg * H + h] = l; }
    float4 o; o.x = a0; o.y = a1; o.z = a2; o.w = a3;
    ((float4*)pf)[(size_t)wg * (C / 4) + t] = o;
}

// ---------------------------------------------------------------------------
// k3: per (b,h): combine NC chunk partials -> normalized fbar[128],
// then ctx[b,h,e] = sum_d fbar[d]*Wv[e,d] + bv[e].
// ---------------------------------------------------------------------------
__global__ __launch_bounds__(128) void k3_combine(
    const float* __restrict__ pm, const float* __restrict__ pl,
    const float* __restrict__ pf, const float* __restrict__ Wv,
    const float* __restrict__ bv, float* __restrict__ ctx, int NC) {
    int bh = blockIdx.x;             // b*H + h
    int b = bh >> 3, h = bh & 7;
    int t = threadIdx.x;             // 0..127
    __shared__ float wsh[64];        // NC <= 64
    __shared__ float fsh[HD];

    float M = -1e30f;
    for (int i = 0; i < NC; ++i)
        M = fmaxf(M, pm[(b * NC + i) * H + h]);   // broadcast loads
    if (t < NC) wsh[t] = __expf(pm[(b * NC + t) * H + h] - M);
    __syncthreads();
    float L = 0.f;
    for (int i = 0; i < NC; ++i)
        L += pl[(b * NC + i) * H + h] * wsh[i];
    float acc = 0.f;
    for (int i = 0; i < NC; ++i)
        acc += pf[(size_t)(b * NC + i) * C + h * HD + t] * wsh[i];
    fsh[t] = acc / L;
    __syncthreads();
    float s = 0.f;
#pragma unroll 8
    for (int d = 0; d < HD; ++d)
        s += fsh[d] * Wv[t * HD + d];
    ctx[bh * HD + t] = s + bv[t];
}

// ---------------------------------------------------------------------------
// k4: out[b,s,c] = features[b,s,c] + ctx[b,c]   (float4 streaming)
// ---------------------------------------------------------------------------
__global__ __launch_bounds__(256) void k4_epilogue(
    const float* __restrict__ feat, const float* __restrict__ ctx,
    float* __restrict__ out) {
    size_t i = (size_t)blockIdx.x * blockDim.x + threadIdx.x;  // float4 index
    float4 f = ((const float4*)feat)[i];
    size_t b  = i >> 19;          // / (S*C/4) = 524288
    size_t c4 = i & 255;          // % (C/4)
    float4 cv = ((const float4*)ctx)[b * (C / 4) + c4];
    float4 o; o.x = f.x + cv.x; o.y = f.y + cv.y;
    o.z = f.z + cv.z; o.w = f.w + cv.w;
    ((float4*)out)[i] = o;
}

extern "C" void kernel_launch(void* const* d_in, const int* in_sizes, int n_in,
                              void* d_out, int out_size, void* d_ws, size_t ws_size,
                              hipStream_t stream) {
    const float* feat = (const float*)d_in[0];
    const float* pref = (const float*)d_in[1];
    const float* Wq   = (const float*)d_in[2];
    const float* bq   = (const float*)d_in[3];
    const float* Wk   = (const float*)d_in[4];
    // d_in[5] = bk (unused: softmax shift-invariant)
    const float* Wv   = (const float*)d_in[6];
    const float* bv   = (const float*)d_in[7];
    float* out = (float*)d_out;

    // Choose chunks-per-batch NC to fit workspace (prefer 64 for occupancy).
    int NC = 64;
    auto need = [](int nc) {
        return (size_t)(B * H * HD + B * C + 2 * B * nc * H + (size_t)B * nc * C) * 4;
    };
    while (NC > 1 && need(NC) > ws_size) NC >>= 1;
    int R = S / NC;

    float* ws  = (float*)d_ws;
    float* qk  = ws;                  // B*H*HD   = 16384 floats
    float* ctx = qk + B * H * HD;     // B*C      = 16384
    float* pm  = ctx + B * C;         // B*NC*H
    float* pl  = pm + B * NC * H;     // B*NC*H
    float* pf  = pl + B * NC * H;     // B*NC*C

    k1_qk<<<B * H, HD, 0, stream>>>(pref, Wq, bq, Wk, qk);
    k2_pass<<<B * NC, 256, 0, stream>>>(feat, qk, pm, pl, pf, NC, R);
    k3_combine<<<B * H, HD, 0, stream>>>(pm, pl, pf, Wv, bv, ctx, NC);
    k4_epilogue<<<(B * S * C / 4) / 256, 256, 0, stream>>>(feat, ctx, out);
}